// Round 15
// baseline (189.555 us; speedup 1.0000x reference)
//
#include <hip/hip_runtime.h>

// ---------------- problem constants ----------------
#define BATCH   8
#define LSEQ    1048576          // 1<<20
#define KCONV   500
#define TWIN    2097             // (L-K)/K + 1
#define MROWS   16776            // BATCH*TWIN
#define KDIM    4000             // KCONV * C_IN
#define NDIM    256              // 2 * C_OUT
#define COUT    128
#define VOCAB   257
#define VOCABP  256              // padding row of emb (zeros)

#define BMR     80               // real m-rows per block
#define BMRV    96               // virtual rows (6 tiles; rows 80-95 garbage, discarded)
#define NTILE   210              // ceil(MROWS/80): fits 256 CUs, 1 block/CU
#define SLABP   20               // positions per slab = 160 k = 5 BK32 iters
#define NSLAB   25
#define NG      125              // total BK32 iterations
#define PLANE   (NDIM * 32)      // 8192 shorts per g-plane of Wtf
#define AROWSH  168              // padded shorts per A-slab row (160 + 8)
#define STAGEN  (BMR * SLABP)    // 1600 gathers per slab
#define NTHR    1024             // 16 waves

// ---------------- ws layout (bytes) ----------------
#define WTF_OFF   0ull
#define WTF_BYTES ((size_t)NG * PLANE * 2)                  // 2,048,000
#define POOL_OFF  (WTF_OFF + WTF_BYTES)                     // 1024 floats
#define CNT_OFF   (POOL_OFF + 4096)                         // 1 int

typedef __attribute__((ext_vector_type(8))) __bf16 bf16x8;
typedef __attribute__((ext_vector_type(4))) float  floatx4;

__device__ inline unsigned short f2bf(float f) {
    union { float f; unsigned u; } c; c.f = f;
    return (unsigned short)((c.u + 0x7FFFu + ((c.u >> 16) & 1u)) >> 16);
}
__device__ inline unsigned pack2(float lo, float hi) {
    return (unsigned)f2bf(lo) | ((unsigned)f2bf(hi) << 16);
}

// barrier that waits ONLY for LDS ops — leaves global (B/x prefetch) loads in flight
#define LDS_BARRIER() asm volatile("s_waitcnt lgkmcnt(0)\n\ts_barrier" ::: "memory")

// ---------------- kernel 1: frag-major weights + zero pool/counter ----------------
// Wtf[g][n][kk] = w_n[e=(g*32+kk)&7][p=(g*32+kk)>>3]
__global__ __launch_bounds__(256) void wprep_kernel(const float* __restrict__ w1,
                                                    const float* __restrict__ w2,
                                                    unsigned short* __restrict__ Wtf,
                                                    float* __restrict__ pool,
                                                    int* __restrict__ cnt) {
    const int n   = blockIdx.x;                        // 0..255
    const int tid = threadIdx.x;
    __shared__ float tile[KDIM];                       // 16 KB
    const float* src = (n < COUT) ? (w1 + (size_t)n * KDIM)
                                  : (w2 + (size_t)(n - COUT) * KDIM);
    for (int i = tid; i < KDIM; i += 256) tile[i] = src[i];
    __syncthreads();
    for (int i = tid; i < KDIM; i += 256) {
        int g = i >> 5, kk = i & 31;
        Wtf[(size_t)g * PLANE + n * 32 + kk] = f2bf(tile[(i & 7) * KCONV + (i >> 3)]);
    }
    if (n == 0) {
        if (tid < 256) ((float4*)pool)[tid] = float4{0.f, 0.f, 0.f, 0.f};
        if (tid == 0) *cnt = 0;
    }
}

// ---------------- kernel 2: fused embed + full-K GEMM + gate + max-pool + head ----------------
// ROUND 15 — 16 WAVES / BLOCK AT CONSTANT PER-CU LDS TRAFFIC. r14 confirmed
// the r10 structure at 78us gemm, where the wall (7580 cyc/slab) is 1.9x the
// busiest pipe (LDS ~4000) -> latency-bound at 2 waves/SIMD. r5 showed more
// BLOCKS/CU doubles LDS traffic (loss); more WAVES/block keeps traffic ~flat:
// 1024 thr = 16 waves = 8 col-groups x 2 row-groups over a VIRTUAL 96-row
// tile (real 80; row-group 1's third tile computes discarded garbage ->
// uniform code, no divergence, no r11 allocator trap). Per wave acc[3][2]=24
// regs (vs r10's 40), af[3]/kt -> static pressure BELOW r10's 68. 4 waves/
// SIMD double the latency-hiding candidates on the af->MFMA and gather
// chains. Accepted costs: +20% af reads (240 vs 200 b128/slab), +20% matrix
// work (garbage tile, pipe at ~8% has room), 2x B-L1 (2500 cyc, slack).
// Grid stays 210 -> no CU-idle regression. TRIPWIRES: VGPR<=84, WRITE~1MB.
// Retained: staggered staging (2 slots now: reads kt0/kt1 under MFMAs,
// writes kt1/kt2), 16B table, compute-first ordering, lgkm-only barrier, x
// prefetch a slab ahead, fused head with relaxed device-scope sync.
__global__ __launch_bounds__(NTHR) void gemm_kernel(const int* __restrict__ x,
                                                    const float* __restrict__ emb,
                                                    const unsigned short* __restrict__ Wtf,
                                                    const float* __restrict__ b1,
                                                    const float* __restrict__ b2,
                                                    float* __restrict__ pool,
                                                    int* __restrict__ cnt,
                                                    const float* __restrict__ wd1,
                                                    const float* __restrict__ bd1,
                                                    const float* __restrict__ wd2,
                                                    const float* __restrict__ bd2,
                                                    float* __restrict__ out) {
    __shared__ __align__(16) unsigned short tableL[VOCAB * 8];    // 4112 B
    __shared__ __align__(16) unsigned short As[2][BMRV * AROWSH]; // 2 x 31.5 KB

    const int tid  = threadIdx.x;
    const int lane = tid & 63;
    const int wv   = tid >> 6;                         // 0..15
    const int m0   = blockIdx.x * BMR;
    const int r16  = lane & 15;
    const int q    = lane >> 4;                        // 0..3
    const int cwv  = wv & 7;                           // col-group 0..7
    const int rg   = wv >> 3;                          // row-group 0..1

    // ---- build bf16 emb table in LDS (16B entries) ----
    if (tid < VOCAB) {
        const float4* er = (const float4*)(emb + tid * 8);
        float4 a = er[0], b = er[1];
        uint4 u;
        u.x = pack2(a.x, a.y); u.y = pack2(a.z, a.w);
        u.z = pack2(b.x, b.y); u.w = pack2(b.z, b.w);
        *(uint4*)(tableL + tid * 8) = u;
    }

    // ---- staging roles: thread handles idx = tid + 1024*l (idx < 1600) ----
    const int* xptr[2];
    int        loff[2];
    bool       sval[2];
    bool       sact[2];
#pragma unroll
    for (int l = 0; l < 2; ++l) {
        sact[l] = (l < 1) || (tid < STAGEN - NTHR);     // slot 1: tids 0..575
        int idx = tid + NTHR * l;
        sval[l] = (idx < STAGEN);
        int ic  = sval[l] ? idx : 0;
        int row = ic / SLABP;
        int pos = ic - row * SLABP;
        int am  = m0 + row;
        bool av = sval[l] && (am < MROWS);
        sval[l] = av;
        int amc = av ? am : 0;
        int b   = amc / TWIN;
        int t   = amc - b * TWIN;
        xptr[l] = x + ((size_t)b * LSEQ + (size_t)t * KCONV + pos);
        loff[l] = row * AROWSH + pos * 8;
    }

    // ---- compute role: column o (+128 gate partner), 3 row tiles ----
    const int o = cwv * 16 + r16;                      // 0..127
    const size_t boff0 = (size_t)o * 32 + q * 8;
    const size_t boff1 = (size_t)(o + 128) * 32 + q * 8;
    const int rbase = rg * 3;                          // tiles rbase..rbase+2

    floatx4 acc[3][2];
#pragma unroll
    for (int i = 0; i < 3; ++i) { acc[i][0] = floatx4{0,0,0,0}; acc[i][1] = floatx4{0,0,0,0}; }

    // ---- x values for slab 0 ----
    int xv[2], xn[2];
#pragma unroll
    for (int l = 0; l < 2; ++l) xv[l] = sval[l] ? xptr[l][0] : VOCABP;
    __syncthreads();                                   // table visible

    // ---- stage slab 0 into buf 0 (unavoidable burst before first compute) ----
#pragma unroll
    for (int l = 0; l < 2; ++l) {
        if (sact[l]) {
            uint4 g = *(const uint4*)(tableL + xv[l] * 8);
            *(uint4*)((unsigned short*)As + loff[l]) = g;
        }
    }
#pragma unroll
    for (int l = 0; l < 2; ++l) xv[l] = sval[l] ? xptr[l][SLABP] : VOCABP;
    LDS_BARRIER();

    // ---- B prefetch prologue: g=0,1 ----
    bf16x8 bc0[2], bc1[2], bc2[2] = {};
    bc0[0] = *(const bf16x8*)(Wtf + boff0);
    bc0[1] = *(const bf16x8*)(Wtf + boff1);
    bc1[0] = *(const bf16x8*)(Wtf + PLANE + boff0);
    bc1[1] = *(const bf16x8*)(Wtf + PLANE + boff1);

    int buf = 0;
    for (int s = 0; s < NSLAB; ++s) {
        // issue x loads for slab s+2 early (vmcnt; a full slab of cover)
        if (s + 2 < NSLAB) {
#pragma unroll
            for (int l = 0; l < 2; ++l)
                xn[l] = sval[l] ? xptr[l][(s + 2) * SLABP] : VOCABP;
        }

        const unsigned short* Asb  = (const unsigned short*)As + buf * (BMRV * AROWSH);
        unsigned short*       dstS = (unsigned short*)As + (buf ^ 1) * (BMRV * AROWSH);
        const bool stg = (s + 1 < NSLAB);
        uint4 gr[2];

        // ---- 5 BK=32 iterations; B depth-2 pipeline; staggered staging ----
#pragma unroll
        for (int kt = 0; kt < 5; ++kt) {
            const int g = s * 5 + kt;
            if (g + 2 < NG) {
                const unsigned short* Wp = Wtf + (size_t)(g + 2) * PLANE;
                bc2[0] = *(const bf16x8*)(Wp + boff0);
                bc2[1] = *(const bf16x8*)(Wp + boff1);
            }
            bf16x8 af[3];
#pragma unroll
            for (int i = 0; i < 3; ++i)
                af[i] = *(const bf16x8*)(Asb + ((rbase + i) * 16 + r16) * AROWSH
                                         + (kt * 4 + q) * 8);

            // gather-READ slot kt (kt<2): issued with this kt's af reads —
            // the MFMA's counted lgkm wait only covers af, gather stays
            // outstanding.
            if (kt < 2 && stg && sact[kt])
                gr[kt] = *(const uint4*)(tableL + xv[kt] * 8);

#pragma unroll
            for (int i = 0; i < 3; ++i) {
                acc[i][0] = __builtin_amdgcn_mfma_f32_16x16x32_bf16(af[i], bc0[0], acc[i][0], 0, 0, 0);
                acc[i][1] = __builtin_amdgcn_mfma_f32_16x16x32_bf16(af[i], bc0[1], acc[i][1], 0, 0, 0);
            }
            bc0[0] = bc1[0]; bc0[1] = bc1[1];
            bc1[0] = bc2[0]; bc1[1] = bc2[1];

            // gather-WRITE slot kt-1 (kt 1..2): data arrived a full kt ago
            if (kt >= 1 && kt <= 2 && stg && sact[kt - 1])
                *(uint4*)(dstS + loff[kt - 1]) = gr[kt - 1];
        }
#pragma unroll
        for (int l = 0; l < 2; ++l) xv[l] = xn[l];
        LDS_BARRIER();
        buf ^= 1;
    }

    // ---- epilogue: gate + per-batch max in registers, atomicMax flush ----
    // C/D layout: col = lane&15 (n), row = q*4 + reg (m). Skip virtual rows
    // (lrow >= BMR: row-group 1's third tile is the discarded garbage).
    const float b1v = b1[o], b2v = b2[o];
    float cur = 0.0f;
    int curb  = (m0 + rbase * 16 + q * 4) / TWIN;
#pragma unroll
    for (int i = 0; i < 3; ++i) {
#pragma unroll
        for (int rgi = 0; rgi < 4; ++rgi) {
            const int lrow = (rbase + i) * 16 + q * 4 + rgi;
            const int row  = m0 + lrow;
            if (lrow < BMR && row < MROWS) {
                const int bb = row / TWIN;
                if (bb != curb) {
                    atomicMax((int*)&pool[curb * COUT + o], __float_as_int(cur));
                    cur = 0.0f; curb = bb;
                }
                const float c1 = acc[i][0][rgi] + b1v;
                const float c2 = acc[i][1][rgi] + b2v;
                const float g  = fmaxf(c1, 0.0f) / (1.0f + __expf(-c2));
                cur = fmaxf(cur, g);
            }
        }
    }
    atomicMax((int*)&pool[curb * COUT + o], __float_as_int(cur));

    // ---- fused head: last block to finish does the dense layers ----
    asm volatile("s_waitcnt vmcnt(0)" ::: "memory");
    __syncthreads();
    __shared__ int lastFlag;
    if (tid == 0) {
        int prev = __hip_atomic_fetch_add(cnt, 1, __ATOMIC_RELAXED, __HIP_MEMORY_SCOPE_AGENT);
        lastFlag = (prev == NTILE - 1) ? 1 : 0;
    }
    __syncthreads();
    if (!lastFlag) return;

    // reuse As as scratch: poolL[1024] + red[8][128]
    float* poolL = (float*)As;
    float* red   = poolL + BATCH * COUT;
    poolL[tid] = __int_as_float(
        __hip_atomic_load((int*)&pool[tid], __ATOMIC_RELAXED, __HIP_MEMORY_SCOPE_AGENT));
    __syncthreads();

    if (tid < COUT) {
        const int j = tid;
        const float wj = wd2[j];
#pragma unroll
        for (int b = 0; b < BATCH; ++b) {
            float s = bd1[j];
            for (int i = 0; i < COUT; ++i) s += poolL[b * COUT + i] * wd1[j * COUT + i];
            red[b * COUT + j] = fmaxf(s, 0.0f) * wj;
        }
    }
    __syncthreads();
    if (tid < BATCH) {
        float s = 0.0f;
        for (int i = 0; i < COUT; ++i) s += red[tid * COUT + i];
        out[tid] = 1.0f / (1.0f + expf(-(s + bd2[0])));
    }
}

// ---------------- launch ----------------
extern "C" void kernel_launch(void* const* d_in, const int* in_sizes, int n_in,
                              void* d_out, int out_size, void* d_ws, size_t ws_size,
                              hipStream_t stream) {
    const int*   x   = (const int*)d_in[0];
    const float* emb = (const float*)d_in[1];
    const float* w1  = (const float*)d_in[2];
    const float* b1  = (const float*)d_in[3];
    const float* w2  = (const float*)d_in[4];
    const float* b2  = (const float*)d_in[5];
    const float* wd1 = (const float*)d_in[6];
    const float* bd1 = (const float*)d_in[7];
    const float* wd2 = (const float*)d_in[8];
    const float* bd2 = (const float*)d_in[9];
    float* out = (float*)d_out;

    unsigned short* Wtf  = (unsigned short*)((char*)d_ws + WTF_OFF);
    float*          pool = (float*)((char*)d_ws + POOL_OFF);
    int*            cnt  = (int*)((char*)d_ws + CNT_OFF);

    wprep_kernel<<<dim3(NDIM), dim3(256), 0, stream>>>(w1, w2, Wtf, pool, cnt);
    gemm_kernel<<<dim3(NTILE), dim3(NTHR), 0, stream>>>(x, emb, Wtf, b1, b2, pool, cnt,
                                                        wd1, bd1, wd2, bd2, out);
}

// Round 16
// 159.242 us; speedup vs baseline: 1.1904x; 1.1904x over previous
//
#include <hip/hip_runtime.h>

// ---------------- problem constants ----------------
#define BATCH   8
#define LSEQ    1048576          // 1<<20
#define KCONV   500
#define TWIN    2097             // (L-K)/K + 1
#define MROWS   16776            // BATCH*TWIN
#define KDIM    4000             // KCONV * C_IN
#define NDIM    256              // 2 * C_OUT
#define COUT    128
#define VOCAB   257
#define VOCABP  256              // padding row of emb (zeros)

#define BMR     80               // m-rows per block (5 x 16)
#define NTILE   210              // ceil(MROWS/80): fits 256 CUs, 1 block/CU
#define SLABP   20               // positions per slab = 160 k = 5 BK32 iters
#define NSLAB   25
#define NG      125              // total BK32 iterations
#define PLANE   (NDIM * 32)      // 8192 shorts per g-plane of Wtf
#define AROWSH  168              // padded shorts per A-slab row (160 + 8)
#define STAGEN  (BMR * SLABP)    // 1600 gathers per slab

// ---------------- ws layout (bytes) ----------------
#define WTF_OFF   0ull
#define WTF_BYTES ((size_t)NG * PLANE * 2)                  // 2,048,000
#define POOL_OFF  (WTF_OFF + WTF_BYTES)                     // 1024 floats
#define CNT_OFF   (POOL_OFF + 4096)                         // 1 int

typedef __attribute__((ext_vector_type(8))) __bf16 bf16x8;
typedef __attribute__((ext_vector_type(4))) float  floatx4;

__device__ inline unsigned short f2bf(float f) {
    union { float f; unsigned u; } c; c.f = f;
    return (unsigned short)((c.u + 0x7FFFu + ((c.u >> 16) & 1u)) >> 16);
}
__device__ inline unsigned pack2(float lo, float hi) {
    return (unsigned)f2bf(lo) | ((unsigned)f2bf(hi) << 16);
}

// barrier that waits ONLY for LDS ops — leaves global (B/x prefetch) loads in flight
#define LDS_BARRIER() asm volatile("s_waitcnt lgkmcnt(0)\n\ts_barrier" ::: "memory")

// ---------------- kernel 1: frag-major weights + zero pool/counter ----------------
// Wtf[g][n][kk] = w_n[e=(g*32+kk)&7][p=(g*32+kk)>>3]
__global__ __launch_bounds__(256) void wprep_kernel(const float* __restrict__ w1,
                                                    const float* __restrict__ w2,
                                                    unsigned short* __restrict__ Wtf,
                                                    float* __restrict__ pool,
                                                    int* __restrict__ cnt) {
    const int n   = blockIdx.x;                        // 0..255
    const int tid = threadIdx.x;
    __shared__ float tile[KDIM];                       // 16 KB
    const float* src = (n < COUT) ? (w1 + (size_t)n * KDIM)
                                  : (w2 + (size_t)(n - COUT) * KDIM);
    for (int i = tid; i < KDIM; i += 256) tile[i] = src[i];
    __syncthreads();
    for (int i = tid; i < KDIM; i += 256) {
        int g = i >> 5, kk = i & 31;
        Wtf[(size_t)g * PLANE + n * 32 + kk] = f2bf(tile[(i & 7) * KCONV + (i >> 3)]);
    }
    if (n == 0) {
        if (tid < 256) ((float4*)pool)[tid] = float4{0.f, 0.f, 0.f, 0.f};
        if (tid == 0) *cnt = 0;
    }
}

// ---------------- kernel 2: fused embed + full-K GEMM + gate + max-pool + head ----------------
// FINAL (r10/r14 configuration — best verified, 158.96us; reproduced 159.4).
// Complete structure ledger (16 rounds of counter evidence):
//  * staggered staging: gather-read at kt=l issued under that kt's MFMAs,
//    gather-write at kt=l+1 (lgkm in-order -> both free). +8us vs burst.
//  * 16B table entries: single ds_read_b128 gather (36B stride RAISED
//    conflicts 5.4M->6.7M).
//  * compute-first ordering + lgkm-only barrier: B/x global prefetches stay
//    in flight across slab boundaries; staging drains into the barrier.
//  * fused head with RELAXED device-scope sync: atomicMax is device-scope on
//    CDNA; vmcnt(0) + __syncthreads + relaxed agent fetch_add. (threadfence/
//    ACQ_REL cost ~45us in L2 writebacks; cooperative grid.sync ~25us
//    in-kernel + ~35us runtime.)
//  * 1 block/CU x 8 waves x BMR=80 is the occupancy optimum: 2+ blocks/CU
//    oversubscribes the LDS pipe (r5, -50us); 16 waves/block doubles barrier
//    skew + gather contention + partial spill (r15, -30us).
//  * C_w=64 remap halves af traffic (conflicts 3.3M, verified 3x) but the
//    allocator pins ~84-88 VGPR and spills ~8MB scratch in every code shape
//    (r1/r11/r12) -> unreachable at HIP source level.
//  * af pipelining: full rotation spills (r9); af[0]-only is TLP-hidden
//    neutral (r13).
// Remaining gap to the 20us MFMA floor is latency/serialization that no
// measured wave/block configuration reduces; ~78us of total is fixed
// harness/launch overhead (minimal at 2 launches).
__global__ __launch_bounds__(512) void gemm_kernel(const int* __restrict__ x,
                                                   const float* __restrict__ emb,
                                                   const unsigned short* __restrict__ Wtf,
                                                   const float* __restrict__ b1,
                                                   const float* __restrict__ b2,
                                                   float* __restrict__ pool,
                                                   int* __restrict__ cnt,
                                                   const float* __restrict__ wd1,
                                                   const float* __restrict__ bd1,
                                                   const float* __restrict__ wd2,
                                                   const float* __restrict__ bd2,
                                                   float* __restrict__ out) {
    __shared__ __align__(16) unsigned short tableL[VOCAB * 8];   // 4112 B
    __shared__ __align__(16) unsigned short As[2][BMR * AROWSH]; // 2 x 26.25 KB

    const int tid  = threadIdx.x;
    const int lane = tid & 63;
    const int wv   = tid >> 6;                         // 0..7
    const int m0   = blockIdx.x * BMR;
    const int r16  = lane & 15;
    const int q    = lane >> 4;                        // 0..3

    // ---- build bf16 emb table in LDS (16B entries) ----
    if (tid < VOCAB) {
        const float4* er = (const float4*)(emb + tid * 8);
        float4 a = er[0], b = er[1];
        uint4 u;
        u.x = pack2(a.x, a.y); u.y = pack2(a.z, a.w);
        u.z = pack2(b.x, b.y); u.w = pack2(b.z, b.w);
        *(uint4*)(tableL + tid * 8) = u;
    }

    // ---- staging roles: thread handles idx = tid + 512*l (idx < 1600) ----
    const int* xptr[4];
    int        loff[4];
    bool       sval[4];
    bool       sact[4];
#pragma unroll
    for (int l = 0; l < 4; ++l) {
        sact[l] = (l < 3) || (tid < STAGEN - 3 * 512);  // slot 3: tids 0..63 only
        int idx = tid + 512 * l;
        sval[l] = (idx < STAGEN);
        int ic  = sval[l] ? idx : 0;
        int row = ic / SLABP;
        int pos = ic - row * SLABP;
        int am  = m0 + row;
        bool av = sval[l] && (am < MROWS);
        sval[l] = av;
        int amc = av ? am : 0;
        int b   = amc / TWIN;
        int t   = amc - b * TWIN;
        xptr[l] = x + ((size_t)b * LSEQ + (size_t)t * KCONV + pos);
        loff[l] = row * AROWSH + pos * 8;
    }

    // ---- compute role ----
    const int o = wv * 16 + r16;                       // 0..127
    const size_t boff0 = (size_t)o * 32 + q * 8;
    const size_t boff1 = (size_t)(o + 128) * 32 + q * 8;

    floatx4 acc[5][2];
#pragma unroll
    for (int i = 0; i < 5; ++i) { acc[i][0] = floatx4{0,0,0,0}; acc[i][1] = floatx4{0,0,0,0}; }

    // ---- x values for slab 0 ----
    int xv[4], xn[4];
#pragma unroll
    for (int l = 0; l < 4; ++l) xv[l] = sval[l] ? xptr[l][0] : VOCABP;
    __syncthreads();                                   // table visible

    // ---- stage slab 0 into buf 0 (unavoidable burst before first compute) ----
#pragma unroll
    for (int l = 0; l < 4; ++l) {
        if (sact[l]) {
            uint4 g = *(const uint4*)(tableL + xv[l] * 8);
            *(uint4*)((unsigned short*)As + loff[l]) = g;
        }
    }
#pragma unroll
    for (int l = 0; l < 4; ++l) xv[l] = sval[l] ? xptr[l][SLABP] : VOCABP;
    LDS_BARRIER();

    // ---- B prefetch prologue: g=0,1 ----
    bf16x8 bc0[2], bc1[2], bc2[2] = {};
    bc0[0] = *(const bf16x8*)(Wtf + boff0);
    bc0[1] = *(const bf16x8*)(Wtf + boff1);
    bc1[0] = *(const bf16x8*)(Wtf + PLANE + boff0);
    bc1[1] = *(const bf16x8*)(Wtf + PLANE + boff1);

    int buf = 0;
    for (int s = 0; s < NSLAB; ++s) {
        // issue x loads for slab s+2 early (vmcnt; a full slab of cover)
        if (s + 2 < NSLAB) {
#pragma unroll
            for (int l = 0; l < 4; ++l)
                xn[l] = sval[l] ? xptr[l][(s + 2) * SLABP] : VOCABP;
        }

        const unsigned short* Asb  = (const unsigned short*)As + buf * (BMR * AROWSH);
        unsigned short*       dstS = (unsigned short*)As + (buf ^ 1) * (BMR * AROWSH);
        const bool stg = (s + 1 < NSLAB);
        uint4 gr[4];

        // ---- 5 BK=32 iterations; B depth-2 register pipeline; staged gathers ----
#pragma unroll
        for (int kt = 0; kt < 5; ++kt) {
            const int g = s * 5 + kt;
            if (g + 2 < NG) {
                const unsigned short* Wp = Wtf + (size_t)(g + 2) * PLANE;
                bc2[0] = *(const bf16x8*)(Wp + boff0);
                bc2[1] = *(const bf16x8*)(Wp + boff1);
            }
            bf16x8 af[5];
#pragma unroll
            for (int i = 0; i < 5; ++i)
                af[i] = *(const bf16x8*)(Asb + (i * 16 + r16) * AROWSH + (kt * 4 + q) * 8);

            // gather-READ slot kt: single b128 from the 16B-stride table;
            // issued with this kt's af reads — the MFMA's counted lgkm wait
            // only covers af, leaving the gather outstanding.
            if (kt < 4 && stg && sact[kt])
                gr[kt] = *(const uint4*)(tableL + xv[kt] * 8);

#pragma unroll
            for (int i = 0; i < 5; ++i) {
                acc[i][0] = __builtin_amdgcn_mfma_f32_16x16x32_bf16(af[i], bc0[0], acc[i][0], 0, 0, 0);
                acc[i][1] = __builtin_amdgcn_mfma_f32_16x16x32_bf16(af[i], bc0[1], acc[i][1], 0, 0, 0);
            }
            bc0[0] = bc1[0]; bc0[1] = bc1[1];
            bc1[0] = bc2[0]; bc1[1] = bc2[1];

            // gather-WRITE slot kt-1: data arrived a full kt ago -> no stall;
            // kt's in-order lgkm traffic already drained the read.
            if (kt >= 1 && stg && sact[kt - 1])
                *(uint4*)(dstS + loff[kt - 1]) = gr[kt - 1];
        }
#pragma unroll
        for (int l = 0; l < 4; ++l) xv[l] = xn[l];
        LDS_BARRIER();
        buf ^= 1;
    }

    // ---- epilogue: gate + per-batch max in registers, atomicMax flush ----
    // C/D layout: col = lane&15 (n), row = q*4 + reg (m).
    const float b1v = b1[o], b2v = b2[o];
    float cur = 0.0f;
    int curb  = (m0 + q * 4) / TWIN;
#pragma unroll
    for (int i = 0; i < 5; ++i) {
#pragma unroll
        for (int rg = 0; rg < 4; ++rg) {
            const int row = m0 + i * 16 + q * 4 + rg;
            if (row < MROWS) {
                const int bb = row / TWIN;
                if (bb != curb) {
                    atomicMax((int*)&pool[curb * COUT + o], __float_as_int(cur));
                    cur = 0.0f; curb = bb;
                }
                const float c1 = acc[i][0][rg] + b1v;
                const float c2 = acc[i][1][rg] + b2v;
                const float g  = fmaxf(c1, 0.0f) / (1.0f + __expf(-c2));
                cur = fmaxf(cur, g);
            }
        }
    }
    atomicMax((int*)&pool[curb * COUT + o], __float_as_int(cur));

    // ---- fused head: last block to finish does the dense layers ----
    asm volatile("s_waitcnt vmcnt(0)" ::: "memory");
    __syncthreads();
    __shared__ int lastFlag;
    if (tid == 0) {
        int prev = __hip_atomic_fetch_add(cnt, 1, __ATOMIC_RELAXED, __HIP_MEMORY_SCOPE_AGENT);
        lastFlag = (prev == NTILE - 1) ? 1 : 0;
    }
    __syncthreads();
    if (!lastFlag) return;

    // reuse As as scratch: poolL[1024] + red[8][128]
    float* poolL = (float*)As;
    float* red   = poolL + BATCH * COUT;
    poolL[tid] = __int_as_float(
        __hip_atomic_load((int*)&pool[tid], __ATOMIC_RELAXED, __HIP_MEMORY_SCOPE_AGENT));
    poolL[tid + 512] = __int_as_float(
        __hip_atomic_load((int*)&pool[tid + 512], __ATOMIC_RELAXED, __HIP_MEMORY_SCOPE_AGENT));
    __syncthreads();

    if (tid < COUT) {
        const int j = tid;
        const float wj = wd2[j];
#pragma unroll
        for (int b = 0; b < BATCH; ++b) {
            float s = bd1[j];
            for (int i = 0; i < COUT; ++i) s += poolL[b * COUT + i] * wd1[j * COUT + i];
            red[b * COUT + j] = fmaxf(s, 0.0f) * wj;
        }
    }
    __syncthreads();
    if (tid < BATCH) {
        float s = 0.0f;
        for (int i = 0; i < COUT; ++i) s += red[tid * COUT + i];
        out[tid] = 1.0f / (1.0f + expf(-(s + bd2[0])));
    }
}

// ---------------- launch ----------------
extern "C" void kernel_launch(void* const* d_in, const int* in_sizes, int n_in,
                              void* d_out, int out_size, void* d_ws, size_t ws_size,
                              hipStream_t stream) {
    const int*   x   = (const int*)d_in[0];
    const float* emb = (const float*)d_in[1];
    const float* w1  = (const float*)d_in[2];
    const float* b1  = (const float*)d_in[3];
    const float* w2  = (const float*)d_in[4];
    const float* b2  = (const float*)d_in[5];
    const float* wd1 = (const float*)d_in[6];
    const float* bd1 = (const float*)d_in[7];
    const float* wd2 = (const float*)d_in[8];
    const float* bd2 = (const float*)d_in[9];
    float* out = (float*)d_out;

    unsigned short* Wtf  = (unsigned short*)((char*)d_ws + WTF_OFF);
    float*          pool = (float*)((char*)d_ws + POOL_OFF);
    int*            cnt  = (int*)((char*)d_ws + CNT_OFF);

    wprep_kernel<<<dim3(NDIM), dim3(256), 0, stream>>>(w1, w2, Wtf, pool, cnt);
    gemm_kernel<<<dim3(NTILE), dim3(512), 0, stream>>>(x, emb, Wtf, b1, b2, pool, cnt,
                                                       wd1, bd1, wd2, bd2, out);
}